// Round 13
// baseline (1551.401 us; speedup 1.0000x reference)
//
#include <hip/hip_runtime.h>

#define NHID    1024
#define BATCH   128
#define LSTEPS  1000
#define DTC     0.042f
#define THETA   1.0f
#define TAUM    20.0f
#define LISTCAP 1032

// lgkm-only barrier: __syncthreads() would drain vmcnt(0) AND lgkmcnt(0).
// The loop's cross-thread communication is LDS-only, so waiting lgkm only
// is sufficient for visibility; in-flight global loads (x prefetch) cross
// the barrier without forcing a drain.
#define BAR() asm volatile("s_waitcnt lgkmcnt(0)\n\ts_barrier" ::: "memory")

// One block per batch element; thread h owns hidden unit h (16 waves/CU).
// Binary-spike matmuls = sparse row gathers over a combined LDS offset list
// (ascending j -> f32 add order identical to R1/R3/R9). R13 = R9 + lgkm-only
// loop barriers. Everything else identical to the 1512us champion.
__global__ __launch_bounds__(1024) void coesn_sim(
    const float* __restrict__ x,        // (B, L, 1)
    const float* __restrict__ x2h,      // (1, H)
    const float* __restrict__ h2h,      // (H, H)
    const float* __restrict__ bias,     // (H)
    const float* __restrict__ lif2hrf,  // (H, H)
    const float* __restrict__ gamma_,   // (H)
    const float* __restrict__ eps_,     // (H)
    float* __restrict__ out,            // (B, 3H) features
    unsigned int* __restrict__ ws)      // (B, 2) spike counts
{
    const int b    = blockIdx.x;
    const int h    = threadIdx.x;
    const int wv   = h >> 6;
    const int lane = h & 63;
    const int wvs  = __builtin_amdgcn_readfirstlane(wv);

    __shared__ unsigned int Ls[LISTCAP];  // HRF spike row byte-offsets
    __shared__ unsigned int Ll[LISTCAP];  // LIF spike row byte-offsets
    __shared__ int Cs[16], Cl[16];
    __shared__ unsigned int red[16];

    Ls[h] = 0; Ll[h] = 0;                 // stale entries stay in-range forever
    if (h < LISTCAP - 1024) { Ls[1024 + h] = 0; Ll[1024 + h] = 0; }
    if (h < 16) { Cs[h] = 0; Cl[h] = 0; }

    float hy = 0.f, hz = 0.f, v = 0.f, rp = 0.f;
    float hysum = 0.f, hysq = 0.f;
    unsigned int chrf = 0, clif = 0;

    const float g    = gamma_[h];
    const float e    = eps_[h];
    const float bi   = bias[h];
    const float win  = x2h[h];
    const float ref_decay = expf((float)(-0.042 / 0.25));
    const float* xb  = x + (size_t)b * LSTEPS;

    const char* hb = (const char*)h2h     + 4 * (size_t)h;
    const char* lb = (const char*)lif2hrf + 4 * (size_t)h;

    const unsigned long long below = (1ULL << lane) - 1ULL;
    const int l16 = lane & 15;

    int ns = 0;                 // HRF list length (phase A bound); 0 at t=0
    float xv_next = xb[0];      // x prefetch (one step ahead)

    __syncthreads();

    for (int t = 0; t < LSTEPS; ++t) {
        // ---- phase A: cur = x*x2h + bias + sum of spiking h2h rows ----
        const float xv = xv_next;
        xv_next = xb[(t + 1 < LSTEPS) ? (t + 1) : t];   // stays in flight across BARs
        float cur = xv * win + bi;
        for (int k = 0; k < ns; k += 8) {
            const unsigned o0 = Ls[k+0], o1 = Ls[k+1], o2 = Ls[k+2], o3 = Ls[k+3];
            const unsigned o4 = Ls[k+4], o5 = Ls[k+5], o6 = Ls[k+6], o7 = Ls[k+7];
            const float a0 = *(const float*)(hb + o0);
            const float a1 = *(const float*)(hb + o1);
            const float a2 = *(const float*)(hb + o2);
            const float a3 = *(const float*)(hb + o3);
            const float a4 = *(const float*)(hb + o4);
            const float a5 = *(const float*)(hb + o5);
            const float a6 = *(const float*)(hb + o6);
            const float a7 = *(const float*)(hb + o7);
            cur += a0;
            cur += (k+1 < ns) ? a1 : 0.0f;
            cur += (k+2 < ns) ? a2 : 0.0f;
            cur += (k+3 < ns) ? a3 : 0.0f;
            cur += (k+4 < ns) ? a4 : 0.0f;
            cur += (k+5 < ns) ? a5 : 0.0f;
            cur += (k+6 < ns) ? a6 : 0.0f;
            cur += (k+7 < ns) ? a7 : 0.0f;
        }

        // ---- phase B: LIF update + spike + list build ----
        v = v + DTC * (-v / TAUM + cur);
        const float lsp = (v > THETA) ? 1.f : 0.f;
        v -= lsp * THETA;
        clif += (unsigned)lsp;
        const unsigned long long balL = __ballot(lsp > 0.5f);
        if (lane == 0) Cl[wv] = (int)__popcll(balL);
        BAR();
        int cv = Cl[l16];
        int incl = cv;
        #pragma unroll
        for (int d = 1; d < 16; d <<= 1) {
            const int tt = __shfl_up(incl, d, 16);
            incl += (l16 >= d) ? tt : 0;
        }
        int nl  = __builtin_amdgcn_readlane(incl, 15);
        int pre = __builtin_amdgcn_readlane(incl - cv, wvs);
        if (lsp > 0.5f) Ll[pre + (int)__popcll(balL & below)] = (unsigned)(h * 4096);
        BAR();

        // ---- phase C: drive = sum of spiking lif2hrf rows ----
        float dr = 0.f;
        for (int k = 0; k < nl; k += 8) {
            const unsigned o0 = Ll[k+0], o1 = Ll[k+1], o2 = Ll[k+2], o3 = Ll[k+3];
            const unsigned o4 = Ll[k+4], o5 = Ll[k+5], o6 = Ll[k+6], o7 = Ll[k+7];
            const float a0 = *(const float*)(lb + o0);
            const float a1 = *(const float*)(lb + o1);
            const float a2 = *(const float*)(lb + o2);
            const float a3 = *(const float*)(lb + o3);
            const float a4 = *(const float*)(lb + o4);
            const float a5 = *(const float*)(lb + o5);
            const float a6 = *(const float*)(lb + o6);
            const float a7 = *(const float*)(lb + o7);
            dr += a0;
            dr += (k+1 < nl) ? a1 : 0.0f;
            dr += (k+2 < nl) ? a2 : 0.0f;
            dr += (k+3 < nl) ? a3 : 0.0f;
            dr += (k+4 < nl) ? a4 : 0.0f;
            dr += (k+5 < nl) ? a5 : 0.0f;
            dr += (k+6 < nl) ? a6 : 0.0f;
            dr += (k+7 < nl) ? a7 : 0.0f;
        }

        // ---- phase D: HRF update + spike + stats + list build ----
        hz = hz + DTC * (dr - g * hy - e * hz);
        hy = hy + DTC * hz;
        const float sn = ((hy - THETA - rp) > 0.f) ? 1.f : 0.f;
        rp = rp * ref_decay + sn;
        hysum += hy;
        hysq  += hy * hy;
        chrf += (unsigned)sn;
        const unsigned long long balS = __ballot(sn > 0.5f);
        if (lane == 0) Cs[wv] = (int)__popcll(balS);
        BAR();
        cv = Cs[l16];
        incl = cv;
        #pragma unroll
        for (int d = 1; d < 16; d <<= 1) {
            const int tt = __shfl_up(incl, d, 16);
            incl += (l16 >= d) ? tt : 0;
        }
        ns  = __builtin_amdgcn_readlane(incl, 15);
        pre = __builtin_amdgcn_readlane(incl - cv, wvs);
        if (sn > 0.5f) Ls[pre + (int)__popcll(balS & below)] = (unsigned)(h * 4096);
        BAR();
    }

    // ---- epilogue: features ----
    const float Lf   = (float)LSTEPS;
    const float mean = hysum / Lf;
    const float rms  = sqrtf(hysq / Lf + 1e-8f);
    float var = hysq / Lf - mean * mean;
    var = fmaxf(var, 1e-8f);
    float* ob = out + (size_t)b * (3 * NHID);
    ob[h]            = rms;
    ob[NHID + h]     = sqrtf(var);
    ob[2 * NHID + h] = hy;

    // ---- spike-count reduction (exact ints) ----
    unsigned int c = chrf;
    for (int off = 32; off > 0; off >>= 1) c += __shfl_down(c, off, 64);
    if (lane == 0) red[wv] = c;
    __syncthreads();
    if (h == 0) {
        unsigned int tot = 0;
        for (int i = 0; i < 16; ++i) tot += red[i];
        ws[b * 2] = tot;
    }
    __syncthreads();
    c = clif;
    for (int off = 32; off > 0; off >>= 1) c += __shfl_down(c, off, 64);
    if (lane == 0) red[wv] = c;
    __syncthreads();
    if (h == 0) {
        unsigned int tot = 0;
        for (int i = 0; i < 16; ++i) tot += red[i];
        ws[b * 2 + 1] = tot;
    }
}

__global__ void coesn_final(const unsigned int* __restrict__ ws,
                            float* __restrict__ out)
{
    if (threadIdx.x == 0 && blockIdx.x == 0) {
        unsigned long long hrf = 0, lif = 0;
        for (int b = 0; b < BATCH; ++b) {
            hrf += ws[b * 2];
            lif += ws[b * 2 + 1];
        }
        const float denom = (float)BATCH * (float)LSTEPS * (float)NHID;
        const float r_hrf = (float)hrf / denom;
        const float r_lif = (float)lif / denom;
        float* s = out + (size_t)BATCH * 3 * NHID;
        s[0] = r_hrf;
        s[1] = r_hrf;
        s[2] = r_lif;
    }
}

extern "C" void kernel_launch(void* const* d_in, const int* in_sizes, int n_in,
                              void* d_out, int out_size, void* d_ws, size_t ws_size,
                              hipStream_t stream) {
    const float* x       = (const float*)d_in[0];
    const float* x2h     = (const float*)d_in[1];
    const float* h2h     = (const float*)d_in[2];
    const float* bias    = (const float*)d_in[3];
    const float* lif2hrf = (const float*)d_in[4];
    const float* gamma_  = (const float*)d_in[5];
    const float* eps_    = (const float*)d_in[6];
    float* out = (float*)d_out;
    unsigned int* wsp = (unsigned int*)d_ws;

    coesn_sim<<<BATCH, NHID, 0, stream>>>(x, x2h, h2h, bias, lif2hrf, gamma_, eps_, out, wsp);
    coesn_final<<<1, 64, 0, stream>>>(wsp, out);
}